// Round 6
// baseline (526.834 us; speedup 1.0000x reference)
//
#include <hip/hip_runtime.h>

// ---------------------------------------------------------------------------
// 2-layer GCN on MI355X — round 6: XCD-partitioned bucket sort for adjacency.
//   Buckets of 128 nodes; bucket b owned by XCD b&7. Edges appended into
//   bucket regions (L2-local cursors, line-merged writes), then per-bucket
//   ELL build in LDS with coalesced write-out. Gather/MFMA path unchanged.
// ---------------------------------------------------------------------------

#define MD 48        // ELL width; deg ~ Poisson(10), P(deg>=48) ~ 1e-18
#define NBKT 782     // ceil(100000/128)
#define BCAP 1536    // bucket capacity; mean 1279, sd 36 -> +7 sigma

typedef __attribute__((ext_vector_type(8))) short bf16x8;   // 8 bf16 = 4 VGPRs
typedef __attribute__((ext_vector_type(4))) float f32x4;

__device__ inline float bf2f(unsigned short v) {
    unsigned u = (unsigned)v << 16;
    return __builtin_bit_cast(float, u);
}
__device__ inline unsigned short f2bf(float f) {  // round-to-nearest-even
    unsigned u = __builtin_bit_cast(unsigned, f);
    unsigned r = (u + 0x7FFFu + ((u >> 16) & 1u)) >> 16;
    return (unsigned short)r;
}

__global__ __launch_bounds__(256) void k_zero_i32(int* __restrict__ p, int n) {
    int i = blockIdx.x * blockDim.x + threadIdx.x;
    if (i < n) p[i] = 0;
}

// --- phase 1: XCD-partitioned bucket append --------------------------------
// Blocks with (blockIdx&7)==x collectively grid-stride ALL edges, keeping only
// edges whose bucket (dst>>7) has (b&7)==x. Cursor atomics + appended lines
// then stay in one XCD's L2 (blockIdx->XCD is round-robin on MI355X).
__global__ __launch_bounds__(256) void k_bucket_scatter(const int* __restrict__ src,
                                                        const int* __restrict__ dst, int E,
                                                        int* __restrict__ bcnt,
                                                        unsigned* __restrict__ sorted) {
    const int myxcd = blockIdx.x & 7;
    const int vb = blockIdx.x >> 3;        // virtual block within XCD group
    const int nvb = gridDim.x >> 3;
    for (int e = vb * 256 + threadIdx.x; e < E; e += nvb * 256) {
        int d = dst[e];
        int b = d >> 7;
        if ((b & 7) != myxcd) continue;
        int pos = atomicAdd(&bcnt[b], 1);
        if (pos < BCAP)
            sorted[(size_t)b * BCAP + pos] = ((unsigned)(d & 127) << 17) | (unsigned)src[e];
    }
}

// --- phase 2: per-bucket ELL build in LDS, coalesced write-out -------------
// One block per bucket; blockIdx%8 == bucket%8 -> runs on the owner XCD.
// Emits col_ell window, cnt (clamped to MD) and dinv (from true count).
__global__ __launch_bounds__(256) void k_ell_build(const unsigned* __restrict__ sorted,
                                                   const int* __restrict__ bcnt,
                                                   int* __restrict__ col_ell,
                                                   int* __restrict__ cnt,
                                                   float* __restrict__ dinv, int n) {
    __shared__ int scnt[128];
    __shared__ unsigned sell[128 * MD];  // 24.6 KB
    const int tid = threadIdx.x;
    const int b = blockIdx.x;
    if (tid < 128) scnt[tid] = 0;
    for (int i = tid; i < 128 * MD; i += 256) sell[i] = 0;
    __syncthreads();
    const int ne = min(bcnt[b], BCAP);
    for (int i = tid; i < ne; i += 256) {
        unsigned v = sorted[(size_t)b * BCAP + i];
        int dl = v >> 17;
        int s = (int)(v & 0x1FFFFu);
        int p = atomicAdd(&scnt[dl], 1);
        if (p < MD) sell[dl * MD + p] = (unsigned)s;
    }
    __syncthreads();
    const size_t base = (size_t)b * 128 * MD;
    for (int i = tid; i < 128 * MD; i += 256) col_ell[base + i] = (int)sell[i];
    if (tid < 128) {
        int node = b * 128 + tid;
        if (node < n) {
            int c = scnt[tid];
            cnt[node] = min(c, MD);
            dinv[node] = rsqrtf((float)(c + 1));  // +1 = self loop
        }
    }
}

// --- W[K][64] -> transposed hi/lo bf16  Wth/Wtl[64][K]  (truncation split) --
__global__ __launch_bounds__(64) void k_convW(const float* __restrict__ W,
                                              short* __restrict__ Wth,
                                              short* __restrict__ Wtl, int K) {
    int k = blockIdx.x;
    int f = threadIdx.x;
    float v = W[k * 64 + f];
    unsigned b = __builtin_bit_cast(unsigned, v);
    unsigned hb = b & 0xFFFF0000u;
    float d = v - __builtin_bit_cast(float, hb);
    unsigned lb = __builtin_bit_cast(unsigned, d);
    Wth[f * K + k] = (short)(hb >> 16);
    Wtl[f * K + k] = (short)(lb >> 16);
}

// --- G[n,64] = bf16( (X[n,K] @ W[K,64]) * dinv[row] ), A = f32 (hi/lo split)
template <int K>
__global__ __launch_bounds__(256) void k_mm_f32A(const float* __restrict__ X,
                                                 const short* __restrict__ Wth,
                                                 const short* __restrict__ Wtl,
                                                 const float* __restrict__ dinv,
                                                 unsigned short* __restrict__ G, int n) {
    const int lane = threadIdx.x & 63;
    const int w = threadIdx.x >> 6;
    const int r0 = lane & 15;
    const int kq = lane >> 4;
    const int arow = blockIdx.x * 64 + w * 16 + r0;
    const float* xrow = X + (size_t)(arow < n ? arow : n - 1) * K;

    f32x4 acc[4] = {};
#pragma unroll
    for (int kc = 0; kc < K / 32; ++kc) {
        const int ks = kc * 32 + kq * 8;
        float xv[8];
        *(f32x4*)&xv[0] = *(const f32x4*)&xrow[ks];
        *(f32x4*)&xv[4] = *(const f32x4*)&xrow[ks + 4];
        bf16x8 ah, al;
#pragma unroll
        for (int j = 0; j < 8; ++j) {
            unsigned b = __builtin_bit_cast(unsigned, xv[j]);
            unsigned hb = b & 0xFFFF0000u;
            float d = xv[j] - __builtin_bit_cast(float, hb);
            unsigned lb = __builtin_bit_cast(unsigned, d);
            ah[j] = (short)(hb >> 16);
            al[j] = (short)(lb >> 16);
        }
#pragma unroll
        for (int c = 0; c < 4; ++c) {
            bf16x8 bh = *(const bf16x8*)&Wth[(c * 16 + r0) * K + ks];
            bf16x8 bl = *(const bf16x8*)&Wtl[(c * 16 + r0) * K + ks];
            acc[c] = __builtin_amdgcn_mfma_f32_16x16x32_bf16(ah, bh, acc[c], 0, 0, 0);
            acc[c] = __builtin_amdgcn_mfma_f32_16x16x32_bf16(ah, bl, acc[c], 0, 0, 0);
            acc[c] = __builtin_amdgcn_mfma_f32_16x16x32_bf16(al, bh, acc[c], 0, 0, 0);
        }
    }
    const int orow = blockIdx.x * 64 + w * 16 + kq * 4;  // C/D: col=lane&15, row=(lane>>4)*4+reg
#pragma unroll
    for (int rg = 0; rg < 4; ++rg) {
        int gr = orow + rg;
        if (gr < n) {
            float di = dinv[gr];
#pragma unroll
            for (int c = 0; c < 4; ++c)
                G[(size_t)gr * 64 + c * 16 + r0] = f2bf(acc[c][rg] * di);
        }
    }
}

// --- G[n,64] = bf16( (A[n,64] @ W[64,64]) * dinv[row] ), A = bf16 (exact) ---
__global__ __launch_bounds__(256) void k_mm_bf16A(const unsigned short* __restrict__ A,
                                                  const short* __restrict__ Wth,
                                                  const short* __restrict__ Wtl,
                                                  const float* __restrict__ dinv,
                                                  unsigned short* __restrict__ G, int n) {
    constexpr int K = 64;
    const int lane = threadIdx.x & 63;
    const int w = threadIdx.x >> 6;
    const int r0 = lane & 15;
    const int kq = lane >> 4;
    const int arow = blockIdx.x * 64 + w * 16 + r0;
    const unsigned short* ar = A + (size_t)(arow < n ? arow : n - 1) * K;

    f32x4 acc[4] = {};
#pragma unroll
    for (int kc = 0; kc < K / 32; ++kc) {
        const int ks = kc * 32 + kq * 8;
        bf16x8 a = *(const bf16x8*)&ar[ks];
#pragma unroll
        for (int c = 0; c < 4; ++c) {
            bf16x8 bh = *(const bf16x8*)&Wth[(c * 16 + r0) * K + ks];
            bf16x8 bl = *(const bf16x8*)&Wtl[(c * 16 + r0) * K + ks];
            acc[c] = __builtin_amdgcn_mfma_f32_16x16x32_bf16(a, bh, acc[c], 0, 0, 0);
            acc[c] = __builtin_amdgcn_mfma_f32_16x16x32_bf16(a, bl, acc[c], 0, 0, 0);
        }
    }
    const int orow = blockIdx.x * 64 + w * 16 + kq * 4;
#pragma unroll
    for (int rg = 0; rg < 4; ++rg) {
        int gr = orow + rg;
        if (gr < n) {
            float di = dinv[gr];
#pragma unroll
            for (int c = 0; c < 4; ++c)
                G[(size_t)gr * 64 + c * 16 + r0] = f2bf(acc[c][rg] * di);
        }
    }
}

// --- ELL gather: dest[i,:] = act( dinv[i]*(g[i,:] + Σ_p g[col_ell[i,p],:]) + b )
template <bool RELU, bool OUTBF>
__global__ __launch_bounds__(256) void k_gather_ell(const unsigned short* __restrict__ g,
                                                    const float* __restrict__ dinv,
                                                    const int* __restrict__ cntArr,
                                                    const int* __restrict__ col_ell,
                                                    const float* __restrict__ bias,
                                                    void* __restrict__ dest, int n) {
    const int node = blockIdx.x * 4 + (threadIdx.x >> 6);
    if (node >= n) return;
    const int lane = threadIdx.x & 63;
    const int grp = lane >> 4;   // 0..3 : edge sub-group
    const int fl = lane & 15;    // feature quad: feats [fl*4, fl*4+4)
    const int cnt = cntArr[node];
    const int myidx = col_ell[(size_t)node * MD + lane];  // lanes>=MD: pad, unconsumed

    float a0 = 0.f, a1 = 0.f, a2 = 0.f, a3 = 0.f;
    if (grp == 0) {  // self loop row
        uint2 u = *(const uint2*)&g[(size_t)node * 64 + fl * 4];
        a0 = bf2f((unsigned short)(u.x & 0xFFFF));
        a1 = bf2f((unsigned short)(u.x >> 16));
        a2 = bf2f((unsigned short)(u.y & 0xFFFF));
        a3 = bf2f((unsigned short)(u.y >> 16));
    }
    for (int j4 = 0; j4 < cnt; j4 += 4) {
        int j = j4 + grp;
        int s = __shfl(myidx, j);
        if (j < cnt) {
            uint2 u = *(const uint2*)&g[(size_t)s * 64 + fl * 4];
            a0 += bf2f((unsigned short)(u.x & 0xFFFF));
            a1 += bf2f((unsigned short)(u.x >> 16));
            a2 += bf2f((unsigned short)(u.y & 0xFFFF));
            a3 += bf2f((unsigned short)(u.y >> 16));
        }
    }
    a0 += __shfl_xor(a0, 16); a0 += __shfl_xor(a0, 32);
    a1 += __shfl_xor(a1, 16); a1 += __shfl_xor(a1, 32);
    a2 += __shfl_xor(a2, 16); a2 += __shfl_xor(a2, 32);
    a3 += __shfl_xor(a3, 16); a3 += __shfl_xor(a3, 32);

    if (grp == 0) {
        const float di = dinv[node];
        const f32x4 bv = *(const f32x4*)&bias[fl * 4];
        float v0 = fmaf(a0, di, bv[0]);
        float v1 = fmaf(a1, di, bv[1]);
        float v2 = fmaf(a2, di, bv[2]);
        float v3 = fmaf(a3, di, bv[3]);
        if (RELU) {
            v0 = fmaxf(v0, 0.f); v1 = fmaxf(v1, 0.f);
            v2 = fmaxf(v2, 0.f); v3 = fmaxf(v3, 0.f);
        }
        if (OUTBF) {
            uint2 o;
            o.x = (unsigned)f2bf(v0) | ((unsigned)f2bf(v1) << 16);
            o.y = (unsigned)f2bf(v2) | ((unsigned)f2bf(v3) << 16);
            *(uint2*)&((unsigned short*)dest)[(size_t)node * 64 + fl * 4] = o;
        } else {
            f32x4 o = {v0, v1, v2, v3};
            *(f32x4*)&((float*)dest)[(size_t)node * 64 + fl * 4] = o;
        }
    }
}

extern "C" void kernel_launch(void* const* d_in, const int* in_sizes, int n_in,
                              void* d_out, int out_size, void* d_ws, size_t ws_size,
                              hipStream_t stream) {
    const float* x  = (const float*)d_in[0];
    const int*   ei = (const int*)d_in[1];
    const float* W1 = (const float*)d_in[2];
    const float* b1 = (const float*)d_in[3];
    const float* W2 = (const float*)d_in[4];
    const float* b2 = (const float*)d_in[5];

    const int N = in_sizes[0] / 128;   // 100000
    const int E = in_sizes[1] / 2;     // 1000000
    const int* src = ei;
    const int* dst = ei + E;
    float* out = (float*)d_out;

    // ws layout (64B-aligned slices)
    char* ws = (char*)d_ws;
    size_t off = 0;
    auto alloc = [&](size_t bytes) {
        void* p = ws + off;
        off += (bytes + 63) & ~(size_t)63;
        return p;
    };
    unsigned short* a1   = (unsigned short*)alloc((size_t)N * 64 * 2);  // bf16 act
    unsigned short* gbuf = (unsigned short*)alloc((size_t)N * 64 * 2);  // bf16 g
    float*    dinv    = (float*)alloc((size_t)N * 4);
    int*      cnt     = (int*)alloc((size_t)N * 4);
    int*      col_ell = (int*)alloc(((size_t)NBKT * 128 * MD + 64) * 4);  // bucket-padded
    int*      bcnt    = (int*)alloc((size_t)(NBKT + 2) * 4);
    unsigned* sorted  = (unsigned*)alloc((size_t)NBKT * BCAP * 4);
    short*    W1th    = (short*)alloc((size_t)64 * 128 * 2);
    short*    W1tl    = (short*)alloc((size_t)64 * 128 * 2);
    short*    W2th    = (short*)alloc((size_t)64 * 64 * 2);
    short*    W2tl    = (short*)alloc((size_t)64 * 64 * 2);

    const int NB_MM = (N + 63) / 64;
    const int NB_G  = (N + 3) / 4;

    // adjacency: bucket append (XCD-local) -> per-bucket ELL build
    k_zero_i32<<<4, 256, 0, stream>>>(bcnt, NBKT + 2);
    k_bucket_scatter<<<2048, 256, 0, stream>>>(src, dst, E, bcnt, sorted);
    k_ell_build<<<NBKT, 256, 0, stream>>>(sorted, bcnt, col_ell, cnt, dinv, N);

    // weight prep (tiny)
    k_convW<<<128, 64, 0, stream>>>(W1, W1th, W1tl, 128);
    k_convW<<<64, 64, 0, stream>>>(W2, W2th, W2tl, 64);

    // ---- layer 1 ----
    k_mm_f32A<128><<<NB_MM, 256, 0, stream>>>(x, W1th, W1tl, dinv, gbuf, N);
    k_gather_ell<true, true><<<NB_G, 256, 0, stream>>>(gbuf, dinv, cnt, col_ell, b1, a1, N);

    // ---- layer 2 ----
    k_mm_bf16A<<<NB_MM, 256, 0, stream>>>(a1, W2th, W2tl, dinv, gbuf, N);
    k_gather_ell<false, false><<<NB_G, 256, 0, stream>>>(gbuf, dinv, cnt, col_ell, b2, out, N);
}

// Round 7
// 236.288 us; speedup vs baseline: 2.2296x; 2.2296x over previous
//
#include <hip/hip_runtime.h>

// ---------------------------------------------------------------------------
// 2-layer GCN on MI355X — round 7: round-5 ELL structure (bucket sort REVERTED:
// 782-way atomic fan-in = 1280-deep same-address chains @ ~300ns = 375us).
//   + fill ∥ mm1 fused kernel (dinv decoupled from matmuls)
//   + 8-edge-parallel gather with uint4 loads.
//   g = X W (unscaled bf16); out[i] = act( dinv[i]*(dinv[i]*g[i] + Σ dinv[s]*g[s]) + b )
// ---------------------------------------------------------------------------

#define MD 48        // ELL width; deg ~ Poisson(10), P(deg>=48) ~ 1e-18
#define FILLB 1024   // fill blocks in fused kernel (~4 edges/thread)

typedef __attribute__((ext_vector_type(8))) short bf16x8;   // 8 bf16 = 4 VGPRs
typedef __attribute__((ext_vector_type(4))) float f32x4;

__device__ inline float bf2f(unsigned short v) {
    unsigned u = (unsigned)v << 16;
    return __builtin_bit_cast(float, u);
}
__device__ inline unsigned short f2bf(float f) {  // round-to-nearest-even
    unsigned u = __builtin_bit_cast(unsigned, f);
    unsigned r = (u + 0x7FFFu + ((u >> 16) & 1u)) >> 16;
    return (unsigned short)r;
}

__global__ __launch_bounds__(256) void k_zero_i32(int* __restrict__ p, int n) {
    int i = blockIdx.x * blockDim.x + threadIdx.x;
    if (i < n) p[i] = 0;
}

__global__ __launch_bounds__(256) void k_dinv(const int* __restrict__ cnt,
                                              float* __restrict__ dinv, int n) {
    int i = blockIdx.x * blockDim.x + threadIdx.x;
    if (i < n) dinv[i] = rsqrtf((float)(cnt[i] + 1));  // +1 = self loop
}

// --- W[K][64] -> transposed hi/lo bf16  Wth/Wtl[64][K]  (truncation split) --
__global__ __launch_bounds__(64) void k_convW(const float* __restrict__ W,
                                              short* __restrict__ Wth,
                                              short* __restrict__ Wtl, int K) {
    int k = blockIdx.x;
    int f = threadIdx.x;
    float v = W[k * 64 + f];
    unsigned b = __builtin_bit_cast(unsigned, v);
    unsigned hb = b & 0xFFFF0000u;
    float d = v - __builtin_bit_cast(float, hb);
    unsigned lb = __builtin_bit_cast(unsigned, d);
    Wth[f * K + k] = (short)(hb >> 16);
    Wtl[f * K + k] = (short)(lb >> 16);
}

// --- mm1 body: G[row,64] = bf16( X[row,0:K] @ W ), f32 A hi/lo 3-term MFMA --
template <int K>
__device__ inline void mm_f32A_body(int bid, const float* __restrict__ X,
                                    const short* __restrict__ Wth,
                                    const short* __restrict__ Wtl,
                                    unsigned short* __restrict__ G, int n) {
    const int lane = threadIdx.x & 63;
    const int w = threadIdx.x >> 6;
    const int r0 = lane & 15;
    const int kq = lane >> 4;
    const int arow = bid * 64 + w * 16 + r0;
    const float* xrow = X + (size_t)(arow < n ? arow : n - 1) * K;

    f32x4 acc[4] = {};
#pragma unroll
    for (int kc = 0; kc < K / 32; ++kc) {
        const int ks = kc * 32 + kq * 8;
        float xv[8];
        *(f32x4*)&xv[0] = *(const f32x4*)&xrow[ks];
        *(f32x4*)&xv[4] = *(const f32x4*)&xrow[ks + 4];
        bf16x8 ah, al;
#pragma unroll
        for (int j = 0; j < 8; ++j) {
            unsigned b = __builtin_bit_cast(unsigned, xv[j]);
            unsigned hb = b & 0xFFFF0000u;
            float d = xv[j] - __builtin_bit_cast(float, hb);
            unsigned lb = __builtin_bit_cast(unsigned, d);
            ah[j] = (short)(hb >> 16);
            al[j] = (short)(lb >> 16);
        }
#pragma unroll
        for (int c = 0; c < 4; ++c) {
            bf16x8 bh = *(const bf16x8*)&Wth[(c * 16 + r0) * K + ks];
            bf16x8 bl = *(const bf16x8*)&Wtl[(c * 16 + r0) * K + ks];
            acc[c] = __builtin_amdgcn_mfma_f32_16x16x32_bf16(ah, bh, acc[c], 0, 0, 0);
            acc[c] = __builtin_amdgcn_mfma_f32_16x16x32_bf16(ah, bl, acc[c], 0, 0, 0);
            acc[c] = __builtin_amdgcn_mfma_f32_16x16x32_bf16(al, bh, acc[c], 0, 0, 0);
        }
    }
    const int orow = bid * 64 + w * 16 + kq * 4;  // C/D: col=lane&15, row=(lane>>4)*4+reg
#pragma unroll
    for (int rg = 0; rg < 4; ++rg) {
        int gr = orow + rg;
        if (gr < n) {
#pragma unroll
            for (int c = 0; c < 4; ++c)
                G[(size_t)gr * 64 + c * 16 + r0] = f2bf(acc[c][rg]);
        }
    }
}

// --- fused: blocks [0,FILLB) fill ELL (latency-bound); rest run mm1 --------
// Independent: mm1 no longer reads dinv/cnt (g is unscaled).
template <int K>
__global__ __launch_bounds__(256) void k_fill_mm1(const int* __restrict__ src,
                                                  const int* __restrict__ dst, int E,
                                                  int* __restrict__ cnt,
                                                  int* __restrict__ col_ell,
                                                  const float* __restrict__ X,
                                                  const short* __restrict__ Wth,
                                                  const short* __restrict__ Wtl,
                                                  unsigned short* __restrict__ G, int n) {
    if (blockIdx.x < FILLB) {
        for (int e = blockIdx.x * 256 + threadIdx.x; e < E; e += FILLB * 256) {
            int d = dst[e];
            int p = atomicAdd(&cnt[d], 1);
            if (p < MD) col_ell[(size_t)d * MD + p] = src[e];
        }
    } else {
        mm_f32A_body<K>(blockIdx.x - FILLB, X, Wth, Wtl, G, n);
    }
}

// --- G[n,64] = bf16( A[n,64] @ W[64,64] ), A = bf16 exact, 2-term MFMA -----
__global__ __launch_bounds__(256) void k_mm_bf16A(const unsigned short* __restrict__ A,
                                                  const short* __restrict__ Wth,
                                                  const short* __restrict__ Wtl,
                                                  unsigned short* __restrict__ G, int n) {
    constexpr int K = 64;
    const int lane = threadIdx.x & 63;
    const int w = threadIdx.x >> 6;
    const int r0 = lane & 15;
    const int kq = lane >> 4;
    const int arow = blockIdx.x * 64 + w * 16 + r0;
    const unsigned short* ar = A + (size_t)(arow < n ? arow : n - 1) * K;

    f32x4 acc[4] = {};
#pragma unroll
    for (int kc = 0; kc < K / 32; ++kc) {
        const int ks = kc * 32 + kq * 8;
        bf16x8 a = *(const bf16x8*)&ar[ks];
#pragma unroll
        for (int c = 0; c < 4; ++c) {
            bf16x8 bh = *(const bf16x8*)&Wth[(c * 16 + r0) * K + ks];
            bf16x8 bl = *(const bf16x8*)&Wtl[(c * 16 + r0) * K + ks];
            acc[c] = __builtin_amdgcn_mfma_f32_16x16x32_bf16(a, bh, acc[c], 0, 0, 0);
            acc[c] = __builtin_amdgcn_mfma_f32_16x16x32_bf16(a, bl, acc[c], 0, 0, 0);
        }
    }
    const int orow = blockIdx.x * 64 + w * 16 + kq * 4;
#pragma unroll
    for (int rg = 0; rg < 4; ++rg) {
        int gr = orow + rg;
        if (gr < n) {
#pragma unroll
            for (int c = 0; c < 4; ++c)
                G[(size_t)gr * 64 + c * 16 + r0] = f2bf(acc[c][rg]);
        }
    }
}

// --- ELL gather, 8 edges in flight ----------------------------------------
// out[i] = act( dinv[i]*( dinv[i]*g[i] + Σ_p dinv[s_p]*g[s_p] ) + b )
// Wave per node: 8 groups (grp=lane>>3) × 8 feat-lanes (fl=lane&7, uint4=8bf16).
template <bool RELU, bool OUTBF>
__global__ __launch_bounds__(256) void k_gather8(const unsigned short* __restrict__ g,
                                                 const float* __restrict__ dinv,
                                                 const int* __restrict__ cntArr,
                                                 const int* __restrict__ col_ell,
                                                 const float* __restrict__ bias,
                                                 void* __restrict__ dest, int n) {
    const int node = blockIdx.x * 4 + (threadIdx.x >> 6);
    if (node >= n) return;
    const int lane = threadIdx.x & 63;
    const int grp = lane >> 3;   // 0..7 : edge sub-group
    const int fl = lane & 7;     // feature octet [fl*8, fl*8+8)
    const int lc = min(cntArr[node], MD);
    const int myidx = col_ell[(size_t)node * MD + lane];  // lane>=lc: stale, shfl-gated
    const float mydv = dinv[(lane < lc) ? myidx : node];  // guard stale idx

    float acc[8] = {};
    const float dn = dinv[node];
    if (grp == 0) {  // self loop: dinv[node]*g[node]
        uint4 u = *(const uint4*)&g[(size_t)node * 64 + fl * 8];
        acc[0] = dn * bf2f((unsigned short)(u.x & 0xFFFF));
        acc[1] = dn * bf2f((unsigned short)(u.x >> 16));
        acc[2] = dn * bf2f((unsigned short)(u.y & 0xFFFF));
        acc[3] = dn * bf2f((unsigned short)(u.y >> 16));
        acc[4] = dn * bf2f((unsigned short)(u.z & 0xFFFF));
        acc[5] = dn * bf2f((unsigned short)(u.z >> 16));
        acc[6] = dn * bf2f((unsigned short)(u.w & 0xFFFF));
        acc[7] = dn * bf2f((unsigned short)(u.w >> 16));
    }
    for (int j8 = 0; j8 < lc; j8 += 8) {
        int j = j8 + grp;
        int s = __shfl(myidx, j);
        float ds = __shfl(mydv, j);
        if (j < lc) {
            uint4 u = *(const uint4*)&g[(size_t)s * 64 + fl * 8];
            acc[0] = fmaf(ds, bf2f((unsigned short)(u.x & 0xFFFF)), acc[0]);
            acc[1] = fmaf(ds, bf2f((unsigned short)(u.x >> 16)),    acc[1]);
            acc[2] = fmaf(ds, bf2f((unsigned short)(u.y & 0xFFFF)), acc[2]);
            acc[3] = fmaf(ds, bf2f((unsigned short)(u.y >> 16)),    acc[3]);
            acc[4] = fmaf(ds, bf2f((unsigned short)(u.z & 0xFFFF)), acc[4]);
            acc[5] = fmaf(ds, bf2f((unsigned short)(u.z >> 16)),    acc[5]);
            acc[6] = fmaf(ds, bf2f((unsigned short)(u.w & 0xFFFF)), acc[6]);
            acc[7] = fmaf(ds, bf2f((unsigned short)(u.w >> 16)),    acc[7]);
        }
    }
    // reduce across the 8 groups (grp bits = lane[5:3])
#pragma unroll
    for (int k = 0; k < 8; ++k) {
        acc[k] += __shfl_xor(acc[k], 8);
        acc[k] += __shfl_xor(acc[k], 16);
        acc[k] += __shfl_xor(acc[k], 32);
    }
    if (grp == 0) {
        float v[8];
        const float* bv = &bias[fl * 8];
#pragma unroll
        for (int k = 0; k < 8; ++k) {
            v[k] = fmaf(acc[k], dn, bv[k]);
            if (RELU) v[k] = fmaxf(v[k], 0.f);
        }
        if (OUTBF) {
            uint4 o;
            o.x = (unsigned)f2bf(v[0]) | ((unsigned)f2bf(v[1]) << 16);
            o.y = (unsigned)f2bf(v[2]) | ((unsigned)f2bf(v[3]) << 16);
            o.z = (unsigned)f2bf(v[4]) | ((unsigned)f2bf(v[5]) << 16);
            o.w = (unsigned)f2bf(v[6]) | ((unsigned)f2bf(v[7]) << 16);
            *(uint4*)&((unsigned short*)dest)[(size_t)node * 64 + fl * 8] = o;
        } else {
            float* dp = &((float*)dest)[(size_t)node * 64 + fl * 8];
            *(f32x4*)&dp[0] = *(const f32x4*)&v[0];
            *(f32x4*)&dp[4] = *(const f32x4*)&v[4];
        }
    }
}

extern "C" void kernel_launch(void* const* d_in, const int* in_sizes, int n_in,
                              void* d_out, int out_size, void* d_ws, size_t ws_size,
                              hipStream_t stream) {
    const float* x  = (const float*)d_in[0];
    const int*   ei = (const int*)d_in[1];
    const float* W1 = (const float*)d_in[2];
    const float* b1 = (const float*)d_in[3];
    const float* W2 = (const float*)d_in[4];
    const float* b2 = (const float*)d_in[5];

    const int N = in_sizes[0] / 128;   // 100000
    const int E = in_sizes[1] / 2;     // 1000000
    const int* src = ei;
    const int* dst = ei + E;
    float* out = (float*)d_out;

    // ws layout (64B-aligned slices)
    char* ws = (char*)d_ws;
    size_t off = 0;
    auto alloc = [&](size_t bytes) {
        void* p = ws + off;
        off += (bytes + 63) & ~(size_t)63;
        return p;
    };
    unsigned short* a1   = (unsigned short*)alloc((size_t)N * 64 * 2);  // bf16 act
    unsigned short* gbuf = (unsigned short*)alloc((size_t)N * 64 * 2);  // bf16 g
    float* dinv    = (float*)alloc((size_t)N * 4);
    int*   cnt     = (int*)alloc((size_t)N * 4);
    int*   col_ell = (int*)alloc(((size_t)N * MD + 64) * 4);  // +64 pad (64-lane row read)
    short* W1th    = (short*)alloc((size_t)64 * 128 * 2);
    short* W1tl    = (short*)alloc((size_t)64 * 128 * 2);
    short* W2th    = (short*)alloc((size_t)64 * 64 * 2);
    short* W2tl    = (short*)alloc((size_t)64 * 64 * 2);

    const int NB_N  = (N + 255) / 256;
    const int NB_MM = (N + 63) / 64;
    const int NB_G  = (N + 3) / 4;

    k_zero_i32<<<NB_N, 256, 0, stream>>>(cnt, N);
    k_convW<<<128, 64, 0, stream>>>(W1, W1th, W1tl, 128);
    k_convW<<<64, 64, 0, stream>>>(W2, W2th, W2tl, 64);

    // fill ELL (blocks 0..FILLB) ∥ mm1 (remaining blocks) — independent work
    k_fill_mm1<128><<<FILLB + NB_MM, 256, 0, stream>>>(src, dst, E, cnt, col_ell,
                                                       x, W1th, W1tl, gbuf, N);
    k_dinv<<<NB_N, 256, 0, stream>>>(cnt, dinv, N);

    // ---- layer 1 aggregate ----
    k_gather8<true, true><<<NB_G, 256, 0, stream>>>(gbuf, dinv, cnt, col_ell, b1, a1, N);

    // ---- layer 2 ----
    k_mm_bf16A<<<NB_MM, 256, 0, stream>>>(a1, W2th, W2tl, gbuf, N);
    k_gather8<false, false><<<NB_G, 256, 0, stream>>>(gbuf, dinv, cnt, col_ell, b2, out, N);
}

// Round 8
// 194.195 us; speedup vs baseline: 2.7129x; 1.2168x over previous
//
#include <hip/hip_runtime.h>

// ---------------------------------------------------------------------------
// 2-layer GCN on MI355X — round 8: XCD-partitioned ELL fill (per-node cursors,
// fan-in ~10), separate full-parallelism kernels (r7 fusion reverted).
//   g = X W (unscaled bf16); out[i] = act( dinv[i]*(dinv[i]*g[i] + Σ dinv[s]*g[s]) + b )
// ---------------------------------------------------------------------------

#define MD 48        // ELL width; deg ~ Poisson(10), P(deg>=48) ~ 1e-18

typedef __attribute__((ext_vector_type(8))) short bf16x8;   // 8 bf16 = 4 VGPRs
typedef __attribute__((ext_vector_type(4))) float f32x4;

__device__ inline float bf2f(unsigned short v) {
    unsigned u = (unsigned)v << 16;
    return __builtin_bit_cast(float, u);
}
__device__ inline unsigned short f2bf(float f) {  // round-to-nearest-even
    unsigned u = __builtin_bit_cast(unsigned, f);
    unsigned r = (u + 0x7FFFu + ((u >> 16) & 1u)) >> 16;
    return (unsigned short)r;
}

__global__ __launch_bounds__(256) void k_zero_i32(int* __restrict__ p, int n) {
    int i = blockIdx.x * blockDim.x + threadIdx.x;
    if (i < n) p[i] = 0;
}

// --- XCD-partitioned ELL fill ----------------------------------------------
// Group x = blockIdx&7 owns nodes [x*npx, x*npx+npx). Each group scans ALL
// edges (int4 dst loads) and appends only its own. col_ell/cnt region per
// group = 2.4 MB + 50 KB -> exclusive residency in one XCD's 4 MB L2 ->
// line-merged writes, no cross-XCD ping-pong. Per-node cursor fan-in ~10.
// (Partitioning is a locality heuristic; correctness independent of mapping.)
__global__ __launch_bounds__(256) void k_fill_xcd(const int* __restrict__ src,
                                                  const int* __restrict__ dst, int E,
                                                  int* __restrict__ cnt,
                                                  int* __restrict__ col_ell, int npx) {
    const int myxcd = blockIdx.x & 7;
    const int lo = myxcd * npx;
    const int hi = lo + npx;
    const int vb = blockIdx.x >> 3;
    const int nvb = gridDim.x >> 3;
    const int tid = vb * 256 + threadIdx.x;
    const int nthr = nvb * 256;
    for (int base = tid * 4; base < E; base += nthr * 4) {  // E % 4 == 0
        int4 d4 = *(const int4*)&dst[base];
#pragma unroll
        for (int k = 0; k < 4; ++k) {
            int d = (&d4.x)[k];
            if (d >= lo && d < hi) {
                int p = atomicAdd(&cnt[d], 1);
                if (p < MD) col_ell[(size_t)d * MD + p] = src[base + k];
            }
        }
    }
}

__global__ __launch_bounds__(256) void k_dinv(const int* __restrict__ cnt,
                                              float* __restrict__ dinv, int n) {
    int i = blockIdx.x * blockDim.x + threadIdx.x;
    if (i < n) dinv[i] = rsqrtf((float)(cnt[i] + 1));  // +1 = self loop
}

// --- W[K][64] -> transposed hi/lo bf16  Wth/Wtl[64][K]  (truncation split) --
__global__ __launch_bounds__(64) void k_convW(const float* __restrict__ W,
                                              short* __restrict__ Wth,
                                              short* __restrict__ Wtl, int K) {
    int k = blockIdx.x;
    int f = threadIdx.x;
    float v = W[k * 64 + f];
    unsigned b = __builtin_bit_cast(unsigned, v);
    unsigned hb = b & 0xFFFF0000u;
    float d = v - __builtin_bit_cast(float, hb);
    unsigned lb = __builtin_bit_cast(unsigned, d);
    Wth[f * K + k] = (short)(hb >> 16);
    Wtl[f * K + k] = (short)(lb >> 16);
}

// --- G[n,64] = bf16( X[n,K] @ W[K,64] ), A = f32 (hi/lo split, 3-term) -----
template <int K>
__global__ __launch_bounds__(256) void k_mm_f32A(const float* __restrict__ X,
                                                 const short* __restrict__ Wth,
                                                 const short* __restrict__ Wtl,
                                                 unsigned short* __restrict__ G, int n) {
    const int lane = threadIdx.x & 63;
    const int w = threadIdx.x >> 6;
    const int r0 = lane & 15;
    const int kq = lane >> 4;
    const int arow = blockIdx.x * 64 + w * 16 + r0;
    const float* xrow = X + (size_t)(arow < n ? arow : n - 1) * K;

    f32x4 acc[4] = {};
#pragma unroll
    for (int kc = 0; kc < K / 32; ++kc) {
        const int ks = kc * 32 + kq * 8;
        float xv[8];
        *(f32x4*)&xv[0] = *(const f32x4*)&xrow[ks];
        *(f32x4*)&xv[4] = *(const f32x4*)&xrow[ks + 4];
        bf16x8 ah, al;
#pragma unroll
        for (int j = 0; j < 8; ++j) {
            unsigned b = __builtin_bit_cast(unsigned, xv[j]);
            unsigned hb = b & 0xFFFF0000u;
            float d = xv[j] - __builtin_bit_cast(float, hb);
            unsigned lb = __builtin_bit_cast(unsigned, d);
            ah[j] = (short)(hb >> 16);
            al[j] = (short)(lb >> 16);
        }
#pragma unroll
        for (int c = 0; c < 4; ++c) {
            bf16x8 bh = *(const bf16x8*)&Wth[(c * 16 + r0) * K + ks];
            bf16x8 bl = *(const bf16x8*)&Wtl[(c * 16 + r0) * K + ks];
            acc[c] = __builtin_amdgcn_mfma_f32_16x16x32_bf16(ah, bh, acc[c], 0, 0, 0);
            acc[c] = __builtin_amdgcn_mfma_f32_16x16x32_bf16(ah, bl, acc[c], 0, 0, 0);
            acc[c] = __builtin_amdgcn_mfma_f32_16x16x32_bf16(al, bh, acc[c], 0, 0, 0);
        }
    }
    const int orow = blockIdx.x * 64 + w * 16 + kq * 4;  // C/D: col=lane&15, row=(lane>>4)*4+reg
#pragma unroll
    for (int rg = 0; rg < 4; ++rg) {
        int gr = orow + rg;
        if (gr < n) {
#pragma unroll
            for (int c = 0; c < 4; ++c)
                G[(size_t)gr * 64 + c * 16 + r0] = f2bf(acc[c][rg]);
        }
    }
}

// --- G[n,64] = bf16( A[n,64] @ W[64,64] ), A = bf16 exact, 2-term MFMA -----
__global__ __launch_bounds__(256) void k_mm_bf16A(const unsigned short* __restrict__ A,
                                                  const short* __restrict__ Wth,
                                                  const short* __restrict__ Wtl,
                                                  unsigned short* __restrict__ G, int n) {
    constexpr int K = 64;
    const int lane = threadIdx.x & 63;
    const int w = threadIdx.x >> 6;
    const int r0 = lane & 15;
    const int kq = lane >> 4;
    const int arow = blockIdx.x * 64 + w * 16 + r0;
    const unsigned short* ar = A + (size_t)(arow < n ? arow : n - 1) * K;

    f32x4 acc[4] = {};
#pragma unroll
    for (int kc = 0; kc < K / 32; ++kc) {
        const int ks = kc * 32 + kq * 8;
        bf16x8 a = *(const bf16x8*)&ar[ks];
#pragma unroll
        for (int c = 0; c < 4; ++c) {
            bf16x8 bh = *(const bf16x8*)&Wth[(c * 16 + r0) * K + ks];
            bf16x8 bl = *(const bf16x8*)&Wtl[(c * 16 + r0) * K + ks];
            acc[c] = __builtin_amdgcn_mfma_f32_16x16x32_bf16(a, bh, acc[c], 0, 0, 0);
            acc[c] = __builtin_amdgcn_mfma_f32_16x16x32_bf16(a, bl, acc[c], 0, 0, 0);
        }
    }
    const int orow = blockIdx.x * 64 + w * 16 + kq * 4;
#pragma unroll
    for (int rg = 0; rg < 4; ++rg) {
        int gr = orow + rg;
        if (gr < n) {
#pragma unroll
            for (int c = 0; c < 4; ++c)
                G[(size_t)gr * 64 + c * 16 + r0] = f2bf(acc[c][rg]);
        }
    }
}

// --- ELL gather, 8 edges in flight ----------------------------------------
// out[i] = act( dinv[i]*( dinv[i]*g[i] + Σ_p dinv[s_p]*g[s_p] ) + b )
template <bool RELU, bool OUTBF>
__global__ __launch_bounds__(256) void k_gather8(const unsigned short* __restrict__ g,
                                                 const float* __restrict__ dinv,
                                                 const int* __restrict__ cntArr,
                                                 const int* __restrict__ col_ell,
                                                 const float* __restrict__ bias,
                                                 void* __restrict__ dest, int n) {
    const int node = blockIdx.x * 4 + (threadIdx.x >> 6);
    if (node >= n) return;
    const int lane = threadIdx.x & 63;
    const int grp = lane >> 3;   // 0..7 : edge sub-group
    const int fl = lane & 7;     // feature octet [fl*8, fl*8+8)
    const int lc = min(cntArr[node], MD);
    const int myidx = col_ell[(size_t)node * MD + lane];  // lane>=lc: stale, shfl-gated
    const float mydv = dinv[(lane < lc) ? myidx : node];  // guard stale idx

    float acc[8] = {};
    const float dn = dinv[node];
    if (grp == 0) {  // self loop: dinv[node]*g[node]
        uint4 u = *(const uint4*)&g[(size_t)node * 64 + fl * 8];
        acc[0] = dn * bf2f((unsigned short)(u.x & 0xFFFF));
        acc[1] = dn * bf2f((unsigned short)(u.x >> 16));
        acc[2] = dn * bf2f((unsigned short)(u.y & 0xFFFF));
        acc[3] = dn * bf2f((unsigned short)(u.y >> 16));
        acc[4] = dn * bf2f((unsigned short)(u.z & 0xFFFF));
        acc[5] = dn * bf2f((unsigned short)(u.z >> 16));
        acc[6] = dn * bf2f((unsigned short)(u.w & 0xFFFF));
        acc[7] = dn * bf2f((unsigned short)(u.w >> 16));
    }
    for (int j8 = 0; j8 < lc; j8 += 8) {
        int j = j8 + grp;
        int s = __shfl(myidx, j);
        float ds = __shfl(mydv, j);
        if (j < lc) {
            uint4 u = *(const uint4*)&g[(size_t)s * 64 + fl * 8];
            acc[0] = fmaf(ds, bf2f((unsigned short)(u.x & 0xFFFF)), acc[0]);
            acc[1] = fmaf(ds, bf2f((unsigned short)(u.x >> 16)),    acc[1]);
            acc[2] = fmaf(ds, bf2f((unsigned short)(u.y & 0xFFFF)), acc[2]);
            acc[3] = fmaf(ds, bf2f((unsigned short)(u.y >> 16)),    acc[3]);
            acc[4] = fmaf(ds, bf2f((unsigned short)(u.z & 0xFFFF)), acc[4]);
            acc[5] = fmaf(ds, bf2f((unsigned short)(u.z >> 16)),    acc[5]);
            acc[6] = fmaf(ds, bf2f((unsigned short)(u.w & 0xFFFF)), acc[6]);
            acc[7] = fmaf(ds, bf2f((unsigned short)(u.w >> 16)),    acc[7]);
        }
    }
#pragma unroll
    for (int k = 0; k < 8; ++k) {
        acc[k] += __shfl_xor(acc[k], 8);
        acc[k] += __shfl_xor(acc[k], 16);
        acc[k] += __shfl_xor(acc[k], 32);
    }
    if (grp == 0) {
        float v[8];
        const float* bv = &bias[fl * 8];
#pragma unroll
        for (int k = 0; k < 8; ++k) {
            v[k] = fmaf(acc[k], dn, bv[k]);
            if (RELU) v[k] = fmaxf(v[k], 0.f);
        }
        if (OUTBF) {
            uint4 o;
            o.x = (unsigned)f2bf(v[0]) | ((unsigned)f2bf(v[1]) << 16);
            o.y = (unsigned)f2bf(v[2]) | ((unsigned)f2bf(v[3]) << 16);
            o.z = (unsigned)f2bf(v[4]) | ((unsigned)f2bf(v[5]) << 16);
            o.w = (unsigned)f2bf(v[6]) | ((unsigned)f2bf(v[7]) << 16);
            *(uint4*)&((unsigned short*)dest)[(size_t)node * 64 + fl * 8] = o;
        } else {
            float* dp = &((float*)dest)[(size_t)node * 64 + fl * 8];
            *(f32x4*)&dp[0] = *(const f32x4*)&v[0];
            *(f32x4*)&dp[4] = *(const f32x4*)&v[4];
        }
    }
}

extern "C" void kernel_launch(void* const* d_in, const int* in_sizes, int n_in,
                              void* d_out, int out_size, void* d_ws, size_t ws_size,
                              hipStream_t stream) {
    const float* x  = (const float*)d_in[0];
    const int*   ei = (const int*)d_in[1];
    const float* W1 = (const float*)d_in[2];
    const float* b1 = (const float*)d_in[3];
    const float* W2 = (const float*)d_in[4];
    const float* b2 = (const float*)d_in[5];

    const int N = in_sizes[0] / 128;   // 100000
    const int E = in_sizes[1] / 2;     // 1000000
    const int* src = ei;
    const int* dst = ei + E;
    float* out = (float*)d_out;

    // ws layout (64B-aligned slices)
    char* ws = (char*)d_ws;
    size_t off = 0;
    auto alloc = [&](size_t bytes) {
        void* p = ws + off;
        off += (bytes + 63) & ~(size_t)63;
        return p;
    };
    unsigned short* a1   = (unsigned short*)alloc((size_t)N * 64 * 2);  // bf16 act
    unsigned short* gbuf = (unsigned short*)alloc((size_t)N * 64 * 2);  // bf16 g
    float* dinv    = (float*)alloc((size_t)N * 4);
    int*   cnt     = (int*)alloc((size_t)N * 4);
    int*   col_ell = (int*)alloc(((size_t)N * MD + 64) * 4);  // +64 pad (64-lane row read)
    short* W1th    = (short*)alloc((size_t)64 * 128 * 2);
    short* W1tl    = (short*)alloc((size_t)64 * 128 * 2);
    short* W2th    = (short*)alloc((size_t)64 * 64 * 2);
    short* W2tl    = (short*)alloc((size_t)64 * 64 * 2);

    const int NB_N  = (N + 255) / 256;
    const int NB_MM = (N + 63) / 64;
    const int NB_G  = (N + 3) / 4;
    const int npx   = (N + 7) / 8;     // nodes per XCD partition

    k_zero_i32<<<NB_N, 256, 0, stream>>>(cnt, N);
    k_convW<<<128, 64, 0, stream>>>(W1, W1th, W1tl, 128);
    k_convW<<<64, 64, 0, stream>>>(W2, W2th, W2tl, 64);

    // XCD-partitioned ELL fill: 8192 blocks = 8 groups x 1024; each group
    // scans all E edges (int4), keeps its node range (2.4 MB L2-resident).
    k_fill_xcd<<<8192, 256, 0, stream>>>(src, dst, E, cnt, col_ell, npx);
    k_dinv<<<NB_N, 256, 0, stream>>>(cnt, dinv, N);

    // ---- layer 1 ----
    k_mm_f32A<128><<<NB_MM, 256, 0, stream>>>(x, W1th, W1tl, gbuf, N);
    k_gather8<true, true><<<NB_G, 256, 0, stream>>>(gbuf, dinv, cnt, col_ell, b1, a1, N);

    // ---- layer 2 ----
    k_mm_bf16A<<<NB_MM, 256, 0, stream>>>(a1, W2th, W2tl, gbuf, N);
    k_gather8<false, false><<<NB_G, 256, 0, stream>>>(gbuf, dinv, cnt, col_ell, b2, out, N);
}